// Round 13
// baseline (104.019 us; speedup 1.0000x reference)
//
#include <hip/hip_runtime.h>

typedef short short4v __attribute__((ext_vector_type(4)));
typedef short short8 __attribute__((ext_vector_type(8)));
typedef float floatx4 __attribute__((ext_vector_type(4)));

// Native bf16 conversion: compiler emits packed v_cvt_pk_bf16_f32 (RTNE).
__device__ __forceinline__ short f2bf(float f) {
    __bf16 h = (__bf16)f;
    return __builtin_bit_cast(short, h);
}
__device__ __forceinline__ float bf2f(short s) {
    unsigned u = ((unsigned)(unsigned short)s) << 16;
    return __builtin_bit_cast(float, u);
}

// Convert lora_A (4096x64) and lora_B (64x4096) fp32 -> bf16 in MFMA fragment
// layout for mfma_f32_16x16x32_bf16:
//   lane l holds elem[k][c] with c = l&15, k = 8*(l>>4) + j, j=0..7
__global__ __launch_bounds__(256) void conv_ab(
    const float* __restrict__ A, const float* __restrict__ B,
    short* __restrict__ Abf, short* __restrict__ Bbf) {
    int i = blockIdx.x * 256 + threadIdx.x;   // 0 .. 262143
    int j    = i & 7;
    int lane = (i >> 3) & 63;
    int hi   = i >> 9;                        // A: ks*4+nt ; B: ct*2+ks
    int krow = 8 * (lane >> 4) + j;
    int cc   = lane & 15;
    {   // A fragments
        int ks = hi >> 2, nt = hi & 3;
        Abf[i] = f2bf(A[(size_t)(ks * 32 + krow) * 64 + nt * 16 + cc]);
    }
    {   // B fragments
        int ct = hi >> 1, ks = hi & 1;
        Bbf[i] = f2bf(B[(size_t)(ks * 32 + krow) * 4096 + ct * 16 + cc]);
    }
}

// k1: 8 bf16 split-K partials of t = x @ A (R10 best config: 2-deep rotating
// register pipeline). Grid (1024, 2) x 4 waves; wave w owns rows bx*16..+15,
// ksplit p = by*4+w. Operand-SWAPPED mfma -> lane holds 4 consecutive t-cols
// of ONE row -> direct 8B stores. No LDS, no barriers.
__global__ __launch_bounds__(256, 4) void k1_xA(
    const float* __restrict__ x, const float* __restrict__ tw,
    const short* __restrict__ Abf, short* __restrict__ t8) {
    const int lane = threadIdx.x & 63;
    const int wave = threadIdx.x >> 6;
    const int rowbase = blockIdx.x * 16;
    const int rrow = lane & 15;
    const int kgrp = lane >> 4;
    const int p = blockIdx.y * 4 + wave;      // ksplit 0..7
    const int kbase = p * 512;

    const int row = rowbase + rrow;
    const bool active = (tw[row] != 0.0f);
    const floatx4* xv = (const floatx4*)(x + (size_t)row * 4096 + kbase + kgrp * 8);
    // Abf8[(ksg*4+nt)*64 + lane], ksg = kbase/32 + ks
    const short8* ap = (const short8*)Abf + ((size_t)(kbase >> 5) * 256) + lane;

    floatx4 acc0 = {0,0,0,0}, acc1 = {0,0,0,0}, acc2 = {0,0,0,0}, acc3 = {0,0,0,0};

    floatx4 px[2][2];
    short8  pb[2][4];
    #pragma unroll
    for (int s = 0; s < 2; ++s) {
        px[s][0] = (floatx4){0,0,0,0};
        px[s][1] = (floatx4){0,0,0,0};
        if (active) { px[s][0] = xv[s * 8]; px[s][1] = xv[s * 8 + 1]; }
        pb[s][0] = ap[s * 256 + 0 * 64];
        pb[s][1] = ap[s * 256 + 1 * 64];
        pb[s][2] = ap[s * 256 + 2 * 64];
        pb[s][3] = ap[s * 256 + 3 * 64];
    }

    #pragma unroll
    for (int ks = 0; ks < 16; ++ks) {
        const int s = ks & 1;
        short8 xa;
        xa[0] = f2bf(px[s][0][0]); xa[1] = f2bf(px[s][0][1]);
        xa[2] = f2bf(px[s][0][2]); xa[3] = f2bf(px[s][0][3]);
        xa[4] = f2bf(px[s][1][0]); xa[5] = f2bf(px[s][1][1]);
        xa[6] = f2bf(px[s][1][2]); xa[7] = f2bf(px[s][1][3]);
        short8 b0 = pb[s][0], b1 = pb[s][1], b2 = pb[s][2], b3 = pb[s][3];

        if (ks + 2 < 16) {
            if (active) { px[s][0] = xv[(ks + 2) * 8]; px[s][1] = xv[(ks + 2) * 8 + 1]; }
            pb[s][0] = ap[(ks + 2) * 256 + 0 * 64];
            pb[s][1] = ap[(ks + 2) * 256 + 1 * 64];
            pb[s][2] = ap[(ks + 2) * 256 + 2 * 64];
            pb[s][3] = ap[(ks + 2) * 256 + 3 * 64];
        }

        // swapped: A-matrix fragment as A-operand, x fragment as B-operand.
        acc0 = __builtin_amdgcn_mfma_f32_16x16x32_bf16(b0, xa, acc0, 0, 0, 0);
        acc1 = __builtin_amdgcn_mfma_f32_16x16x32_bf16(b1, xa, acc1, 0, 0, 0);
        acc2 = __builtin_amdgcn_mfma_f32_16x16x32_bf16(b2, xa, acc2, 0, 0, 0);
        acc3 = __builtin_amdgcn_mfma_f32_16x16x32_bf16(b3, xa, acc3, 0, 0, 0);
    }

    // D layout: n = lane&15 (token row), m = 4*kgrp + b (t-col within n-tile)
    short* tp = t8 + (size_t)p * (16384 * 64) + (size_t)row * 64 + kgrp * 4;
    floatx4 accs[4] = {acc0, acc1, acc2, acc3};
    #pragma unroll
    for (int nt = 0; nt < 4; ++nt) {
        short4v v;
        v[0] = f2bf(accs[nt][0]); v[1] = f2bf(accs[nt][1]);
        v[2] = f2bf(accs[nt][2]); v[3] = f2bf(accs[nt][3]);
        *(short4v*)(tp + nt * 16) = v;
    }
}

// k1.5: t = sum of 8 bf16 partials (f32 accumulate). 1M elems / 4 per thread.
__global__ __launch_bounds__(256) void k1_sum(
    const short* __restrict__ t8, short* __restrict__ t) {
    const int i = blockIdx.x * 256 + threadIdx.x;   // 0 .. 262143
    const size_t off = (size_t)i * 4;
    float s0 = 0.f, s1 = 0.f, s2 = 0.f, s3 = 0.f;
    #pragma unroll
    for (int p = 0; p < 8; ++p) {
        short4v v = *(const short4v*)(t8 + (size_t)p * (16384 * 64) + off);
        s0 += bf2f(v[0]); s1 += bf2f(v[1]); s2 += bf2f(v[2]); s3 += bf2f(v[3]);
    }
    short4v r;
    r[0] = f2bf(s0); r[1] = f2bf(s1); r[2] = f2bf(s2); r[3] = f2bf(s3);
    *(short4v*)(t + off) = r;
}

// k2: out = (t @ B) * tw * 2, operand-swapped MFMA, double-buffered LDS
// epilogue. 4096 blocks x 4 waves: block = 16 rows x 1024 cols, processed as
// 4 strips of 256 cols. t-fragments loaded ONCE per block (reused 4x); per
// strip: 8 B-frag loads -> 8 MFMA -> LDS buf[s&1] -> barrier -> row-linear
// 256B NT stores. Strip s+1's loads overlap strip s's store drain; 4x fewer
// blocks amortizes ramp/drain (R12 theory: k2 was duty-cycle-limited).
__global__ __launch_bounds__(256, 4) void k2_tB(
    const short* __restrict__ t, const float* __restrict__ tw,
    const short* __restrict__ Bbf, float* __restrict__ out) {
    __shared__ float tile[2][16][260];    // 260: 16B-aligned rows, banks shift 4/row

    const int lane = threadIdx.x & 63;
    const int wave = threadIdx.x >> 6;
    const int rg = blockIdx.x >> 2;       // row group 0..4095? no: 0..1023
    const int cq = blockIdx.x & 3;        // col quarter 0..3
    const int rowbase = rg * 16;
    const int rrow = lane & 15;
    const int kgrp = lane >> 4;
    const int kofs = kgrp * 8;

    // t fragment (MFMA B-operand): lane holds t[rowbase+rrow][kofs+j]
    const short* t0 = t + (size_t)(rowbase + rrow) * 64 + kofs;
    short8 a0 = *(const short8*)t0;
    short8 a1 = *(const short8*)(t0 + 32);

    const float w = tw[rowbase + rrow] * 2.0f;
    const int orow_i = 4 * wave + kgrp;
    float* orow = out + (size_t)(rowbase + orow_i) * 4096;

    #pragma unroll
    for (int s = 0; s < 4; ++s) {
        const int colblk = cq * 1024 + s * 256;
        // B fragments (MFMA A-operand): Bbf8[(ct*2+ks)*64 + lane], ct = col/16
        const short8* bp = (const short8*)Bbf
                         + (size_t)((colblk + wave * 64) >> 4) * 128 + lane;
        #pragma unroll
        for (int nt = 0; nt < 4; ++nt) {
            short8 b0 = bp[(nt * 2 + 0) * 64];
            short8 b1 = bp[(nt * 2 + 1) * 64];
            floatx4 acc = {0, 0, 0, 0};
            // swapped: lane holds out[rrow][wave*64 + nt*16 + kgrp*4 + 0..3]
            acc = __builtin_amdgcn_mfma_f32_16x16x32_bf16(b0, a0, acc, 0, 0, 0);
            acc = __builtin_amdgcn_mfma_f32_16x16x32_bf16(b1, a1, acc, 0, 0, 0);
            acc[0] *= w; acc[1] *= w; acc[2] *= w; acc[3] *= w;
            *(floatx4*)&tile[s & 1][rrow][wave * 64 + nt * 16 + kgrp * 4] = acc;
        }
        __syncthreads();
        // row-linear write-out: lane -> row 4*wave+kgrp, 16B chunk rrow*16B
        // within each 64-float group q: 16 lanes cover 256B contiguous.
        #pragma unroll
        for (int q = 0; q < 4; ++q) {
            const int c = q * 64 + rrow * 4;
            floatx4 v = *(const floatx4*)&tile[s & 1][orow_i][c];
            __builtin_nontemporal_store(v, (floatx4*)(orow + colblk + c));
        }
        // next strip writes the other buffer; its writes follow this barrier,
        // and readers of that buffer finished before their own barrier.
    }
}

extern "C" void kernel_launch(void* const* d_in, const int* in_sizes, int n_in,
                              void* d_out, int out_size, void* d_ws, size_t ws_size,
                              hipStream_t stream) {
    const float* x  = (const float*)d_in[0];   // (8,2048,4096)
    const float* tw = (const float*)d_in[1];   // (8,2048)
    const float* A  = (const float*)d_in[2];   // (4096,64)
    const float* B  = (const float*)d_in[3];   // (64,4096)
    float* out = (float*)d_out;                // (8,2048,4096) fp32

    short* Abf = (short*)d_ws;                 // 512 KB
    short* Bbf = Abf + 262144;                 // 512 KB
    short* t8  = Bbf + 262144;                 // 8 x 16384 x 64 bf16 = 16 MB
    short* t   = t8 + (size_t)8 * 16384 * 64;  // 2 MB

    conv_ab<<<1024, 256, 0, stream>>>(A, B, Abf, Bbf);
    k1_xA<<<dim3(1024, 2), 256, 0, stream>>>(x, tw, Abf, t8);
    k1_sum<<<1024, 256, 0, stream>>>(t8, t);
    k2_tB<<<4096, 256, 0, stream>>>(t, tw, Bbf, out);
}